// Round 9
// baseline (464.560 us; speedup 1.0000x reference)
//
#include <hip/hip_runtime.h>
#include <hip/hip_bf16.h>
#include <math.h>

#define S_LEN 2048
#define BATCH 2
#define EMB   1024
#define NH    16
#define DH    64
#define E3    3072
#define FF    4096
#define PP    64

typedef __bf16 bf16x8 __attribute__((ext_vector_type(8)));
typedef float  floatx4 __attribute__((ext_vector_type(4)));

__device__ __forceinline__ void load_lds16(const void* g, void* l) {
  __builtin_amdgcn_global_load_lds(
      (const __attribute__((address_space(1))) void*)g,
      (__attribute__((address_space(3))) void*)l, 16, 0, 0);
}

// ---------------- fused fp32 -> bf16 convert for the 5 input arrays ----------
__global__ __launch_bounds__(256) void cvt5_kernel(
    const float* __restrict__ a0, const float* __restrict__ a1,
    const float* __restrict__ a2, const float* __restrict__ a3,
    const float* __restrict__ a4,
    __hip_bfloat16* __restrict__ b0, __hip_bfloat16* __restrict__ b1,
    __hip_bfloat16* __restrict__ b2, __hip_bfloat16* __restrict__ b3,
    __hip_bfloat16* __restrict__ b4)
{
  int gid = blockIdx.x;
  const float* src; __hip_bfloat16* dst; int base;
  if (gid < 2048)      { src = a0; dst = b0; base = gid; }
  else if (gid < 3584) { src = a1; dst = b1; base = gid - 2048; }
  else if (gid < 4096) { src = a2; dst = b2; base = gid - 3584; }
  else if (gid < 6144) { src = a3; dst = b3; base = gid - 4096; }
  else                 { src = a4; dst = b4; base = gid - 6144; }
  int i = (base * 256 + threadIdx.x) * 8;
  float4 a = *(const float4*)&src[i];
  float4 b = *(const float4*)&src[i + 4];
  __hip_bfloat16 t[8];
  t[0] = __float2bfloat16(a.x); t[1] = __float2bfloat16(a.y);
  t[2] = __float2bfloat16(a.z); t[3] = __float2bfloat16(a.w);
  t[4] = __float2bfloat16(b.x); t[5] = __float2bfloat16(b.y);
  t[6] = __float2bfloat16(b.z); t[7] = __float2bfloat16(b.w);
  *(float4*)&dst[i] = *(float4*)t;
}

// ---------------- pos-embedding projection + L1 norm -> bf16 peT[b][s][q] ----
__global__ __launch_bounds__(64) void pe_kernel(
    const float* __restrict__ pos_embed, const float* __restrict__ pos_w,
    const float* __restrict__ pos_b, __hip_bfloat16* __restrict__ peT)
{
  __shared__ float pw[PP * PP];
  int tid = threadIdx.x;
  for (int i = 0; i < PP; ++i) pw[i * PP + tid] = pos_w[i * PP + tid];
  __syncthreads();
  int s = blockIdx.x * 64 + tid;
  int b = blockIdx.y;
  float acc[PP];
#pragma unroll
  for (int q = 0; q < PP; ++q) acc[q] = pos_b[q];
  for (int p = 0; p < PP; ++p) {
    float x = pos_embed[(size_t)(b * PP + p) * S_LEN + s];
#pragma unroll
    for (int q = 0; q < PP; ++q) acc[q] += pw[q * PP + p] * x;
  }
  float l1 = 0.f;
#pragma unroll
  for (int q = 0; q < PP; ++q) l1 += fabsf(acc[q]);
  float inv = 1.f / fmaxf(l1, 1e-12f);
  __hip_bfloat16 tmp[PP];
#pragma unroll
  for (int q = 0; q < PP; ++q) tmp[q] = __float2bfloat16(acc[q] * inv);
  float4* dst = (float4*)&peT[((size_t)b * S_LEN + s) * PP];
#pragma unroll
  for (int i = 0; i < 8; ++i) dst[i] = ((float4*)tmp)[i];
}

// ---------------- bf16 MFMA GEMM: C[M,N] = A[M,K] @ W[N,K]^T + bias ----------
// Operand-swapped MFMA: lane owns 4 consecutive output cols of one row.
// If vt != nullptr: N-tiles with col >= 2*EMB write transposed into
// vt[b][c][t] (t = row>>1, b = row&1) instead of Cb — fuses V-transpose.
template <int WR, int WC>
__global__ __launch_bounds__(256) void gemm_bf16(
    const __hip_bfloat16* __restrict__ A, const __hip_bfloat16* __restrict__ W,
    const float* __restrict__ bias, float* __restrict__ Cf,
    __hip_bfloat16* __restrict__ Cb, __hip_bfloat16* __restrict__ vt,
    int M, int N, int K, int relu, int qkscale,
    long strideA, long strideW, long strideC)
{
  constexpr int BM = 2 * WR * 16;
  constexpr int BN = 2 * WC * 16;
  __shared__ __bf16 As[BM * 64];
  __shared__ __bf16 Bs[BN * 64];
  A += (size_t)blockIdx.z * strideA;
  W += (size_t)blockIdx.z * strideW;
  int tid = threadIdx.x;
  int bm = blockIdx.y * BM;
  int bn = blockIdx.x * BN;
  int wave = tid >> 6, lane = tid & 63;
  int wm = (wave & 1) * (WR * 16), wn = (wave >> 1) * (WC * 16);
  int srow = tid >> 3, scb = tid & 7;
  int gcb = scb ^ (srow & 7);
  const __hip_bfloat16* Ap = A + (size_t)(bm + srow) * K + gcb * 8;
  const __hip_bfloat16* Wp = W + (size_t)(bn + srow) * K + gcb * 8;
  __bf16* AsBase = As + tid * 8;
  __bf16* BsBase = Bs + tid * 8;
  int r15 = lane & 15, quad = lane >> 4;

  floatx4 acc[WR * WC];
#pragma unroll
  for (int i = 0; i < WR * WC; ++i) acc[i] = (floatx4){0.f, 0.f, 0.f, 0.f};

  for (int k0 = 0; k0 < K; k0 += 64) {
    __syncthreads();
#pragma unroll
    for (int io = 0; io < BM / 32; ++io)
      load_lds16(Ap + (size_t)(32 * io) * K + k0, AsBase + io * 2048);
#pragma unroll
    for (int io = 0; io < BN / 32; ++io)
      load_lds16(Wp + (size_t)(32 * io) * K + k0, BsBase + io * 2048);
    __syncthreads();
#pragma unroll
    for (int kc = 0; kc < 2; ++kc) {
      bf16x8 af[WR], bfv[WC];
      int kb = kc * 4 + quad;
#pragma unroll
      for (int i = 0; i < WR; ++i) {
        int rowa = wm + i * 16 + r15;
        af[i] = *(const bf16x8*)&As[rowa * 64 + (kb ^ (rowa & 7)) * 8];
      }
#pragma unroll
      for (int j = 0; j < WC; ++j) {
        int rowb = wn + j * 16 + r15;
        bfv[j] = *(const bf16x8*)&Bs[rowb * 64 + (kb ^ (rowb & 7)) * 8];
      }
#pragma unroll
      for (int i = 0; i < WR; ++i)
#pragma unroll
        for (int j = 0; j < WC; ++j)
          acc[i * WC + j] = __builtin_amdgcn_mfma_f32_16x16x32_bf16(
              bfv[j], af[i], acc[i * WC + j], 0, 0, 0);
    }
  }
  // epilogue: lane owns row m = bm+wm+i*16+r15, cols n = bn+wn+j*16+quad*4..+3
  int m0 = bm + wm + r15;
  int n0 = bn + wn + quad * 4;
  float* CfB = Cf ? Cf + (size_t)blockIdx.z * strideC : nullptr;
  __hip_bfloat16* CbB = Cb ? Cb + (size_t)blockIdx.z * strideC : nullptr;
#pragma unroll
  for (int j = 0; j < WC; ++j) {
    int col = n0 + j * 16;
    float4 bv4 = bias ? *(const float4*)&bias[col]
                      : (float4){0.f, 0.f, 0.f, 0.f};
    float scale = (qkscale && col < EMB) ? 0.125f : 1.f;
    bool to_vt = (vt != nullptr) && (col >= 2 * EMB);   // block-uniform
#pragma unroll
    for (int i = 0; i < WR; ++i) {
      int row = m0 + i * 16;
      float v0 = (acc[i * WC + j][0] + bv4.x) * scale;
      float v1 = (acc[i * WC + j][1] + bv4.y) * scale;
      float v2 = (acc[i * WC + j][2] + bv4.z) * scale;
      float v3 = (acc[i * WC + j][3] + bv4.w) * scale;
      if (relu) {
        v0 = fmaxf(v0, 0.f); v1 = fmaxf(v1, 0.f);
        v2 = fmaxf(v2, 0.f); v3 = fmaxf(v3, 0.f);
      }
      if (to_vt) {
        int c0 = col - 2 * EMB;
        int bb_ = row & 1, t = row >> 1;
        __hip_bfloat16* vbase = vt + (size_t)bb_ * EMB * S_LEN + t;
        vbase[(size_t)(c0 + 0) * S_LEN] = __float2bfloat16(v0);
        vbase[(size_t)(c0 + 1) * S_LEN] = __float2bfloat16(v1);
        vbase[(size_t)(c0 + 2) * S_LEN] = __float2bfloat16(v2);
        vbase[(size_t)(c0 + 3) * S_LEN] = __float2bfloat16(v3);
      } else {
        if (CfB) {
          float4 o = {v0, v1, v2, v3};
          *(float4*)&CfB[(size_t)row * N + col] = o;
        }
        if (CbB) {
          __hip_bfloat16 o4[4];
          o4[0] = __float2bfloat16(v0); o4[1] = __float2bfloat16(v1);
          o4[2] = __float2bfloat16(v2); o4[3] = __float2bfloat16(v3);
          *(float2*)&CbB[(size_t)row * N + col] = *(float2*)o4;
        }
      }
    }
  }
}

// ---------------- MFMA flash attention (seed register-prefetch) --------------
// block = 128 q x (h, b); 4 waves x 32 q (2 q-blocks of 16); K-tiles of 64.
// S^T = K Q^T; exp w/o max (scores bounded, clamp 60); per-lane partial sums.
// pos_sim seeds for iter kt+1 are prefetched into registers during iter kt.
__global__ __launch_bounds__(256) void attn_mfma(
    const __hip_bfloat16* __restrict__ qkv,   // [S*B][E3] bf16 (q pre-scaled)
    const __hip_bfloat16* __restrict__ vT,    // [B][EMB][S] bf16
    const float* __restrict__ pos_sim,        // [B][S][S] fp32
    __hip_bfloat16* __restrict__ ctx)         // [S*B][EMB] bf16
{
  __shared__ __bf16 Ks[2][4096];   // 16 KB  [key][d] swizzled
  __shared__ __bf16 Vs[2][4096];   // 16 KB  [d][t]  swizzled
  __shared__ __bf16 Ps[8192];      // 16 KB  per (wave,qb): [query][key] swizzled
  int tid = threadIdx.x;
  int q0 = blockIdx.x * 128, h = blockIdx.y, b = blockIdx.z;
  int w = tid >> 6, lane = tid & 63, quad = lane >> 4, r15 = lane & 15;
  int srow = tid >> 3, scb = tid & 7;
  int x7 = r15 & 7;

  const __hip_bfloat16* kbase = qkv + EMB + (size_t)h * DH;
  const __hip_bfloat16* vbase = vT + ((size_t)b * EMB + h * DH) * S_LEN;

  bf16x8 qa[2][2];
#pragma unroll
  for (int qb = 0; qb < 2; ++qb)
#pragma unroll
    for (int kc = 0; kc < 2; ++kc)
      qa[qb][kc] = *(const bf16x8*)&qkv[
          ((size_t)(q0 + w * 32 + qb * 16 + r15) * BATCH + b) * E3 +
          h * DH + kc * 32 + quad * 8];

#pragma unroll
  for (int i = 0; i < 2; ++i) {
    int row = i * 32 + srow;
    int gcb = scb ^ (row & 7);
    load_lds16(kbase + ((size_t)row * BATCH + b) * E3 + gcb * 8,
               Ks[0] + i * 2048 + tid * 8);
    load_lds16(vbase + (size_t)row * S_LEN + gcb * 8,
               Vs[0] + i * 2048 + tid * 8);
  }

  floatx4 of[2][4];
#pragma unroll
  for (int qb = 0; qb < 2; ++qb)
#pragma unroll
    for (int j = 0; j < 4; ++j) of[qb][j] = (floatx4){0.f, 0.f, 0.f, 0.f};
  float lp[2] = {0.f, 0.f};

  const float* psb[2];
#pragma unroll
  for (int qb = 0; qb < 2; ++qb)
    psb[qb] = pos_sim + ((size_t)(b * S_LEN + q0 + w * 32 + qb * 16 + r15)) * S_LEN
              + quad * 4;
  __bf16* pw0 = Ps + (w * 2 + 0) * 1024;
  __bf16* pw1 = Ps + (w * 2 + 1) * 1024;

  // seeds for iter 0
  floatx4 ps[2][4];
#pragma unroll
  for (int qb = 0; qb < 2; ++qb)
#pragma unroll
    for (int j = 0; j < 4; ++j)
      ps[qb][j] = *(const floatx4*)(psb[qb] + j * 16);
  __syncthreads();

  for (int kt = 0; kt < 32; ++kt) {
    int cur = kt & 1;
    int t0 = kt * 64;
    // ---- stage next K/V tile ----
    if (kt < 31) {
      int tn = t0 + 64;
      int nb = cur ^ 1;
#pragma unroll
      for (int i = 0; i < 2; ++i) {
        int row = i * 32 + srow;
        int gcb = scb ^ (row & 7);
        load_lds16(kbase + ((size_t)(tn + row) * BATCH + b) * E3 + gcb * 8,
                   Ks[nb] + i * 2048 + tid * 8);
        load_lds16(vbase + (size_t)row * S_LEN + tn + gcb * 8,
                   Vs[nb] + i * 2048 + tid * 8);
      }
    }
    // ---- prefetch next-iter pos_sim seeds into registers ----
    floatx4 psn[2][4];
    if (kt < 31) {
#pragma unroll
      for (int qb = 0; qb < 2; ++qb)
#pragma unroll
        for (int j = 0; j < 4; ++j)
          psn[qb][j] = *(const floatx4*)(psb[qb] + t0 + 64 + j * 16);
    }

    // ---- S^T = K Q^T + pos_sim (seeds already in registers) ----
    floatx4 sf[2][4];
#pragma unroll
    for (int qb = 0; qb < 2; ++qb)
#pragma unroll
      for (int j = 0; j < 4; ++j) sf[qb][j] = ps[qb][j];
#pragma unroll
    for (int j = 0; j < 4; ++j) {
      int rowk = j * 16 + r15;
      bf16x8 kf0 = *(const bf16x8*)&Ks[cur][rowk * 64 + (quad ^ (rowk & 7)) * 8];
      bf16x8 kf1 = *(const bf16x8*)&Ks[cur][rowk * 64 + ((4 + quad) ^ (rowk & 7)) * 8];
#pragma unroll
      for (int qb = 0; qb < 2; ++qb) {
        sf[qb][j] = __builtin_amdgcn_mfma_f32_16x16x32_bf16(kf0, qa[qb][0], sf[qb][j], 0, 0, 0);
        sf[qb][j] = __builtin_amdgcn_mfma_f32_16x16x32_bf16(kf1, qa[qb][1], sf[qb][j], 0, 0, 0);
      }
    }

    // ---- exp (no max), per-lane l, pack P^T -> per-(wave,qb) LDS ----
#pragma unroll
    for (int qb = 0; qb < 2; ++qb) {
      __bf16* pwq = qb ? pw1 : pw0;
#pragma unroll
      for (int j = 0; j < 4; ++j) {
        float e0 = __expf(fminf(sf[qb][j][0], 60.f));
        float e1 = __expf(fminf(sf[qb][j][1], 60.f));
        float e2 = __expf(fminf(sf[qb][j][2], 60.f));
        float e3 = __expf(fminf(sf[qb][j][3], 60.f));
        lp[qb] += (e0 + e1) + (e2 + e3);
        __hip_bfloat16 t4[4];
        t4[0] = __float2bfloat16(e0); t4[1] = __float2bfloat16(e1);
        t4[2] = __float2bfloat16(e2); t4[3] = __float2bfloat16(e3);
        int addr = r15 * 64 + (((j * 2 + (quad >> 1)) ^ x7) * 8) + (quad & 1) * 4;
        *(float2*)&pwq[addr] = *(float2*)t4;
      }
    }
    __asm__ volatile("s_waitcnt lgkmcnt(0)" ::: "memory");

    // ---- O^T += V^T P^T ----
    bf16x8 pb00 = *(const bf16x8*)&pw0[r15 * 64 + ((quad ^ x7) * 8)];
    bf16x8 pb01 = *(const bf16x8*)&pw0[r15 * 64 + (((4 + quad) ^ x7) * 8)];
    bf16x8 pb10 = *(const bf16x8*)&pw1[r15 * 64 + ((quad ^ x7) * 8)];
    bf16x8 pb11 = *(const bf16x8*)&pw1[r15 * 64 + (((4 + quad) ^ x7) * 8)];
#pragma unroll
    for (int jd = 0; jd < 4; ++jd) {
      int rowd = jd * 16 + r15;
      bf16x8 vb0 = *(const bf16x8*)&Vs[cur][rowd * 64 + (quad ^ (rowd & 7)) * 8];
      bf16x8 vb1 = *(const bf16x8*)&Vs[cur][rowd * 64 + ((4 + quad) ^ (rowd & 7)) * 8];
      of[0][jd] = __builtin_amdgcn_mfma_f32_16x16x32_bf16(vb0, pb00, of[0][jd], 0, 0, 0);
      of[0][jd] = __builtin_amdgcn_mfma_f32_16x16x32_bf16(vb1, pb01, of[0][jd], 0, 0, 0);
      of[1][jd] = __builtin_amdgcn_mfma_f32_16x16x32_bf16(vb0, pb10, of[1][jd], 0, 0, 0);
      of[1][jd] = __builtin_amdgcn_mfma_f32_16x16x32_bf16(vb1, pb11, of[1][jd], 0, 0, 0);
    }
#pragma unroll
    for (int qb = 0; qb < 2; ++qb)
#pragma unroll
      for (int j = 0; j < 4; ++j) ps[qb][j] = psn[qb][j];
    __syncthreads();
  }

#pragma unroll
  for (int qb = 0; qb < 2; ++qb) {
    float l = lp[qb];
    l += __shfl_xor(l, 16, 64);
    l += __shfl_xor(l, 32, 64);
    float inv = 1.f / l;
    size_t rbase = ((size_t)(q0 + w * 32 + qb * 16 + r15) * BATCH + b) * EMB + h * DH;
#pragma unroll
    for (int jd = 0; jd < 4; ++jd) {
      __hip_bfloat16 o4[4];
      o4[0] = __float2bfloat16(of[qb][jd][0] * inv);
      o4[1] = __float2bfloat16(of[qb][jd][1] * inv);
      o4[2] = __float2bfloat16(of[qb][jd][2] * inv);
      o4[3] = __float2bfloat16(of[qb][jd][3] * inv);
      *(float2*)&ctx[rbase + jd * 16 + quad * 4] = *(float2*)o4;
    }
  }
}

// ---------------- layernorm(x1+x2)*g + b, fp32 out + optional bf16 out -------
__global__ __launch_bounds__(256) void ln_kernel(
    const float* __restrict__ x1, const float* __restrict__ x2,
    const float* __restrict__ g, const float* __restrict__ bb,
    float* __restrict__ out, __hip_bfloat16* __restrict__ out_bf)
{
  int row = blockIdx.x;
  int tid = threadIdx.x;
  const float* p1 = x1 + (size_t)row * EMB;
  const float* p2 = x2 + (size_t)row * EMB;
  float4 v1 = *(const float4*)&p1[tid * 4];
  float4 v2 = *(const float4*)&p2[tid * 4];
  float x[4] = {v1.x + v2.x, v1.y + v2.y, v1.z + v2.z, v1.w + v2.w};
  float s = x[0] + x[1] + x[2] + x[3];
  float s2 = x[0] * x[0] + x[1] * x[1] + x[2] * x[2] + x[3] * x[3];
#pragma unroll
  for (int off = 32; off >= 1; off >>= 1) {
    s  += __shfl_xor(s, off, 64);
    s2 += __shfl_xor(s2, off, 64);
  }
  __shared__ float ws1[4], ws2[4];
  int wid = tid >> 6, lane = tid & 63;
  if (lane == 0) { ws1[wid] = s; ws2[wid] = s2; }
  __syncthreads();
  s  = ws1[0] + ws1[1] + ws1[2] + ws1[3];
  s2 = ws2[0] + ws2[1] + ws2[2] + ws2[3];
  float mean = s * (1.f / EMB);
  float var  = s2 * (1.f / EMB) - mean * mean;
  float inv  = rsqrtf(var + 1e-5f);
  float4 gv = *(const float4*)&g[tid * 4];
  float4 bv = *(const float4*)&bb[tid * 4];
  float4 o;
  o.x = (x[0] - mean) * inv * gv.x + bv.x;
  o.y = (x[1] - mean) * inv * gv.y + bv.y;
  o.z = (x[2] - mean) * inv * gv.z + bv.z;
  o.w = (x[3] - mean) * inv * gv.w + bv.w;
  *(float4*)&out[(size_t)row * EMB + tid * 4] = o;
  if (out_bf) {
    __hip_bfloat16 t[4];
    t[0] = __float2bfloat16(o.x); t[1] = __float2bfloat16(o.y);
    t[2] = __float2bfloat16(o.z); t[3] = __float2bfloat16(o.w);
    *(float2*)&out_bf[(size_t)row * EMB + tid * 4] = *(float2*)t;
  }
}

extern "C" void kernel_launch(void* const* d_in, const int* in_sizes, int n_in,
                              void* d_out, int out_size, void* d_ws, size_t ws_size,
                              hipStream_t stream)
{
  const float* src       = (const float*)d_in[0];
  const float* pos_embed = (const float*)d_in[1];
  const float* in_proj_w = (const float*)d_in[2];
  const float* in_proj_b = (const float*)d_in[3];
  const float* out_w     = (const float*)d_in[4];
  const float* out_b     = (const float*)d_in[5];
  const float* lin1_w    = (const float*)d_in[6];
  const float* lin1_b    = (const float*)d_in[7];
  const float* lin2_w    = (const float*)d_in[8];
  const float* lin2_b    = (const float*)d_in[9];
  const float* ln1_g     = (const float*)d_in[10];
  const float* ln1_b     = (const float*)d_in[11];
  const float* ln2_g     = (const float*)d_in[12];
  const float* ln2_b     = (const float*)d_in[13];
  const float* pos_w     = (const float*)d_in[14];
  const float* pos_b     = (const float*)d_in[15];
  float* out = (float*)d_out;
  float* ws  = (float*)d_ws;

  // ---- workspace layout (float units), peak 31,588,352 floats ≈ 126 MB ----
  __hip_bfloat16* peT    = (__hip_bfloat16*)ws;                // 262,144 el -> 131,072 fl
  float* pos_sim         = ws + 131072;                        // 8,388,608 -> 8,519,680
  __hip_bfloat16* qkv_bf = (__hip_bfloat16*)(ws + 8519680);    // 12,582,912 el -> 14,811,136
  __hip_bfloat16* vT_bf  = (__hip_bfloat16*)(ws + 14811136);   // 4,194,304 el -> 16,908,288
  __hip_bfloat16* src_bf = (__hip_bfloat16*)(ws + 16908288);   // 4,194,304 el -> 19,005,440
  __hip_bfloat16* inw_bf  = (__hip_bfloat16*)(ws + 19005440);  // 3,145,728 el -> 20,578,304
  __hip_bfloat16* outw_bf = (__hip_bfloat16*)(ws + 20578304);  // 1,048,576 el -> 21,102,592
  __hip_bfloat16* ctx_bf = (__hip_bfloat16*)(ws + 21102592);   // 4,194,304 el -> 23,199,744
  __hip_bfloat16* l1w_bf = (__hip_bfloat16*)(ws + 23199744);   // 4,194,304 el -> 25,296,896
  __hip_bfloat16* l2w_bf = (__hip_bfloat16*)(ws + 25296896);   // 4,194,304 el -> 27,394,048
  float* proj            = ws + 27394048;                      // 4,194,304 -> 31,588,352
  // phase-2 reuse (peT/pos_sim/qkv/vT dead after attn):
  __hip_bfloat16* x_bf   = (__hip_bfloat16*)ws;                // 4,194,304 el -> 2,097,152 fl
  float* xbuf            = ws + 2097152;                       // 4,194,304 -> 6,291,456
  __hip_bfloat16* h1_bf  = (__hip_bfloat16*)(ws + 6291456);    // 16,777,216 el -> 14,680,064 fl

  const int M = S_LEN * BATCH;  // 4096 rows, row = s*B + b

  cvt5_kernel<<<8192, 256, 0, stream>>>(
      src, in_proj_w, out_w, lin1_w, lin2_w,
      src_bf, inw_bf, outw_bf, l1w_bf, l2w_bf);
  pe_kernel<<<dim3(S_LEN / 64, BATCH), 64, 0, stream>>>(pos_embed, pos_w, pos_b, peT);
  // pos_sim[b] = peT[b] @ peT[b]^T  (M=N=2048, K=64), fp32 out
  gemm_bf16<4, 4><<<dim3(2048 / 128, 2048 / 128, BATCH), 256, 0, stream>>>(
      peT, peT, nullptr, pos_sim, nullptr, nullptr, 2048, 2048, 64, 0, 0,
      (long)2048 * 64, (long)2048 * 64, (long)2048 * 2048);
  // qkv = src @ in_proj_w^T + b; q pre-scaled 0.125; V cols written to vT_bf
  gemm_bf16<4, 4><<<dim3(E3 / 128, M / 128, 1), 256, 0, stream>>>(
      src_bf, inw_bf, in_proj_b, nullptr, qkv_bf, vT_bf, M, E3, EMB, 0, 1, 0, 0, 0);
  attn_mfma<<<dim3(S_LEN / 128, NH, BATCH), 256, 0, stream>>>(
      qkv_bf, vT_bf, pos_sim, ctx_bf);
  // attn_out = ctx @ out_w^T + b   (N=1024: 64x128 tiles -> 512 blocks)
  gemm_bf16<2, 4><<<dim3(EMB / 128, M / 64, 1), 256, 0, stream>>>(
      ctx_bf, outw_bf, out_b, proj, nullptr, nullptr, M, EMB, EMB, 0, 0, 0, 0, 0);
  ln_kernel<<<dim3(M), 256, 0, stream>>>(src, proj, ln1_g, ln1_b, xbuf, x_bf);
  gemm_bf16<4, 4><<<dim3(FF / 128, M / 128, 1), 256, 0, stream>>>(
      x_bf, l1w_bf, lin1_b, nullptr, h1_bf, nullptr, M, FF, EMB, 1, 0, 0, 0, 0);
  gemm_bf16<2, 4><<<dim3(EMB / 128, M / 64, 1), 256, 0, stream>>>(
      h1_bf, l2w_bf, lin2_b, proj, nullptr, nullptr, M, EMB, FF, 0, 0, 0, 0, 0);
  ln_kernel<<<dim3(M), 256, 0, stream>>>(xbuf, proj, ln2_g, ln2_b, out, nullptr);
}

// Round 10
// 460.076 us; speedup vs baseline: 1.0097x; 1.0097x over previous
//
#include <hip/hip_runtime.h>
#include <hip/hip_bf16.h>
#include <math.h>

#define S_LEN 2048
#define BATCH 2
#define EMB   1024
#define NH    16
#define DH    64
#define E3    3072
#define FF    4096
#define PP    64

typedef __bf16 bf16x8 __attribute__((ext_vector_type(8)));
typedef float  floatx4 __attribute__((ext_vector_type(4)));

__device__ __forceinline__ void load_lds16(const void* g, void* l) {
  __builtin_amdgcn_global_load_lds(
      (const __attribute__((address_space(1))) void*)g,
      (__attribute__((address_space(3))) void*)l, 16, 0, 0);
}

// ---------------- fused fp32 -> bf16 convert for the 5 input arrays ----------
__global__ __launch_bounds__(256) void cvt5_kernel(
    const float* __restrict__ a0, const float* __restrict__ a1,
    const float* __restrict__ a2, const float* __restrict__ a3,
    const float* __restrict__ a4,
    __hip_bfloat16* __restrict__ b0, __hip_bfloat16* __restrict__ b1,
    __hip_bfloat16* __restrict__ b2, __hip_bfloat16* __restrict__ b3,
    __hip_bfloat16* __restrict__ b4)
{
  int gid = blockIdx.x;
  const float* src; __hip_bfloat16* dst; int base;
  if (gid < 2048)      { src = a0; dst = b0; base = gid; }
  else if (gid < 3584) { src = a1; dst = b1; base = gid - 2048; }
  else if (gid < 4096) { src = a2; dst = b2; base = gid - 3584; }
  else if (gid < 6144) { src = a3; dst = b3; base = gid - 4096; }
  else                 { src = a4; dst = b4; base = gid - 6144; }
  int i = (base * 256 + threadIdx.x) * 8;
  float4 a = *(const float4*)&src[i];
  float4 b = *(const float4*)&src[i + 4];
  __hip_bfloat16 t[8];
  t[0] = __float2bfloat16(a.x); t[1] = __float2bfloat16(a.y);
  t[2] = __float2bfloat16(a.z); t[3] = __float2bfloat16(a.w);
  t[4] = __float2bfloat16(b.x); t[5] = __float2bfloat16(b.y);
  t[6] = __float2bfloat16(b.z); t[7] = __float2bfloat16(b.w);
  *(float4*)&dst[i] = *(float4*)t;
}

// ---------------- pos-embedding projection + L1 norm -> bf16 peT[b][s][q] ----
__global__ __launch_bounds__(64) void pe_kernel(
    const float* __restrict__ pos_embed, const float* __restrict__ pos_w,
    const float* __restrict__ pos_b, __hip_bfloat16* __restrict__ peT)
{
  __shared__ float pw[PP * PP];
  int tid = threadIdx.x;
  for (int i = 0; i < PP; ++i) pw[i * PP + tid] = pos_w[i * PP + tid];
  __syncthreads();
  int s = blockIdx.x * 64 + tid;
  int b = blockIdx.y;
  float acc[PP];
#pragma unroll
  for (int q = 0; q < PP; ++q) acc[q] = pos_b[q];
  for (int p = 0; p < PP; ++p) {
    float x = pos_embed[(size_t)(b * PP + p) * S_LEN + s];
#pragma unroll
    for (int q = 0; q < PP; ++q) acc[q] += pw[q * PP + p] * x;
  }
  float l1 = 0.f;
#pragma unroll
  for (int q = 0; q < PP; ++q) l1 += fabsf(acc[q]);
  float inv = 1.f / fmaxf(l1, 1e-12f);
  __hip_bfloat16 tmp[PP];
#pragma unroll
  for (int q = 0; q < PP; ++q) tmp[q] = __float2bfloat16(acc[q] * inv);
  float4* dst = (float4*)&peT[((size_t)b * S_LEN + s) * PP];
#pragma unroll
  for (int i = 0; i < 8; ++i) dst[i] = ((float4*)tmp)[i];
}

// ---------------- bf16 MFMA GEMM: C[M,N] = A[M,K] @ W[N,K]^T + bias ----------
// Operand-swapped MFMA: lane owns 4 consecutive output cols of one row.
// If vt != nullptr: N-tiles with col >= 2*EMB write transposed into
// vt[b][c][t] (t = row>>1, b = row&1) instead of Cb — fuses V-transpose.
template <int WR, int WC>
__global__ __launch_bounds__(256) void gemm_bf16(
    const __hip_bfloat16* __restrict__ A, const __hip_bfloat16* __restrict__ W,
    const float* __restrict__ bias, float* __restrict__ Cf,
    __hip_bfloat16* __restrict__ Cb, __hip_bfloat16* __restrict__ vt,
    int M, int N, int K, int relu, int qkscale,
    long strideA, long strideW, long strideC)
{
  constexpr int BM = 2 * WR * 16;
  constexpr int BN = 2 * WC * 16;
  __shared__ __bf16 As[BM * 64];
  __shared__ __bf16 Bs[BN * 64];
  A += (size_t)blockIdx.z * strideA;
  W += (size_t)blockIdx.z * strideW;
  int tid = threadIdx.x;
  int bm = blockIdx.y * BM;
  int bn = blockIdx.x * BN;
  int wave = tid >> 6, lane = tid & 63;
  int wm = (wave & 1) * (WR * 16), wn = (wave >> 1) * (WC * 16);
  int srow = tid >> 3, scb = tid & 7;
  int gcb = scb ^ (srow & 7);
  const __hip_bfloat16* Ap = A + (size_t)(bm + srow) * K + gcb * 8;
  const __hip_bfloat16* Wp = W + (size_t)(bn + srow) * K + gcb * 8;
  __bf16* AsBase = As + tid * 8;
  __bf16* BsBase = Bs + tid * 8;
  int r15 = lane & 15, quad = lane >> 4;

  floatx4 acc[WR * WC];
#pragma unroll
  for (int i = 0; i < WR * WC; ++i) acc[i] = (floatx4){0.f, 0.f, 0.f, 0.f};

  for (int k0 = 0; k0 < K; k0 += 64) {
    __syncthreads();
#pragma unroll
    for (int io = 0; io < BM / 32; ++io)
      load_lds16(Ap + (size_t)(32 * io) * K + k0, AsBase + io * 2048);
#pragma unroll
    for (int io = 0; io < BN / 32; ++io)
      load_lds16(Wp + (size_t)(32 * io) * K + k0, BsBase + io * 2048);
    __syncthreads();
#pragma unroll
    for (int kc = 0; kc < 2; ++kc) {
      bf16x8 af[WR], bfv[WC];
      int kb = kc * 4 + quad;
#pragma unroll
      for (int i = 0; i < WR; ++i) {
        int rowa = wm + i * 16 + r15;
        af[i] = *(const bf16x8*)&As[rowa * 64 + (kb ^ (rowa & 7)) * 8];
      }
#pragma unroll
      for (int j = 0; j < WC; ++j) {
        int rowb = wn + j * 16 + r15;
        bfv[j] = *(const bf16x8*)&Bs[rowb * 64 + (kb ^ (rowb & 7)) * 8];
      }
#pragma unroll
      for (int i = 0; i < WR; ++i)
#pragma unroll
        for (int j = 0; j < WC; ++j)
          acc[i * WC + j] = __builtin_amdgcn_mfma_f32_16x16x32_bf16(
              bfv[j], af[i], acc[i * WC + j], 0, 0, 0);
    }
  }
  // epilogue: lane owns row m = bm+wm+i*16+r15, cols n = bn+wn+j*16+quad*4..+3
  int m0 = bm + wm + r15;
  int n0 = bn + wn + quad * 4;
  float* CfB = Cf ? Cf + (size_t)blockIdx.z * strideC : nullptr;
  __hip_bfloat16* CbB = Cb ? Cb + (size_t)blockIdx.z * strideC : nullptr;
#pragma unroll
  for (int j = 0; j < WC; ++j) {
    int col = n0 + j * 16;
    float4 bv4 = bias ? *(const float4*)&bias[col]
                      : (float4){0.f, 0.f, 0.f, 0.f};
    float scale = (qkscale && col < EMB) ? 0.125f : 1.f;
    bool to_vt = (vt != nullptr) && (col >= 2 * EMB);   // block-uniform
#pragma unroll
    for (int i = 0; i < WR; ++i) {
      int row = m0 + i * 16;
      float v0 = (acc[i * WC + j][0] + bv4.x) * scale;
      float v1 = (acc[i * WC + j][1] + bv4.y) * scale;
      float v2 = (acc[i * WC + j][2] + bv4.z) * scale;
      float v3 = (acc[i * WC + j][3] + bv4.w) * scale;
      if (relu) {
        v0 = fmaxf(v0, 0.f); v1 = fmaxf(v1, 0.f);
        v2 = fmaxf(v2, 0.f); v3 = fmaxf(v3, 0.f);
      }
      if (to_vt) {
        int c0 = col - 2 * EMB;
        int bb_ = row & 1, t = row >> 1;
        __hip_bfloat16* vbase = vt + (size_t)bb_ * EMB * S_LEN + t;
        vbase[(size_t)(c0 + 0) * S_LEN] = __float2bfloat16(v0);
        vbase[(size_t)(c0 + 1) * S_LEN] = __float2bfloat16(v1);
        vbase[(size_t)(c0 + 2) * S_LEN] = __float2bfloat16(v2);
        vbase[(size_t)(c0 + 3) * S_LEN] = __float2bfloat16(v3);
      } else {
        if (CfB) {
          float4 o = {v0, v1, v2, v3};
          *(float4*)&CfB[(size_t)row * N + col] = o;
        }
        if (CbB) {
          __hip_bfloat16 o4[4];
          o4[0] = __float2bfloat16(v0); o4[1] = __float2bfloat16(v1);
          o4[2] = __float2bfloat16(v2); o4[3] = __float2bfloat16(v3);
          *(float2*)&CbB[(size_t)row * N + col] = *(float2*)o4;
        }
      }
    }
  }
}

// ---------------- MFMA flash attention, 64-q blocks for occupancy ------------
// block = 64 q x (h, b); 4 waves x 16 q; K-tiles of 64; grid = 1024 blocks,
// 40 KB LDS -> 4 blocks/CU (16 waves). S^T = K Q^T; no-max softmax (clamp 60);
// per-lane partial sums. Seeds issued BEFORE staging so their vmcnt wait
// leaves the staging loads in flight (round-6 ordering, verified).
__global__ __launch_bounds__(256) void attn_mfma(
    const __hip_bfloat16* __restrict__ qkv,   // [S*B][E3] bf16 (q pre-scaled)
    const __hip_bfloat16* __restrict__ vT,    // [B][EMB][S] bf16
    const float* __restrict__ pos_sim,        // [B][S][S] fp32
    __hip_bfloat16* __restrict__ ctx)         // [S*B][EMB] bf16
{
  __shared__ __bf16 Ks[2][4096];   // 16 KB  [key][d] swizzled
  __shared__ __bf16 Vs[2][4096];   // 16 KB  [d][t]  swizzled
  __shared__ __bf16 Ps[4096];      //  8 KB  per-wave [query][key] swizzled
  int tid = threadIdx.x;
  int q0 = blockIdx.x * 64, h = blockIdx.y, b = blockIdx.z;
  int w = tid >> 6, lane = tid & 63, quad = lane >> 4, r15 = lane & 15;
  int srow = tid >> 3, scb = tid & 7;
  int x7 = r15 & 7;

  const __hip_bfloat16* kbase = qkv + EMB + (size_t)h * DH;
  const __hip_bfloat16* vbase = vT + ((size_t)b * EMB + h * DH) * S_LEN;

  // ---- Q fragments straight to registers (B-operand layout) ----
  bf16x8 qa[2];
#pragma unroll
  for (int kc = 0; kc < 2; ++kc)
    qa[kc] = *(const bf16x8*)&qkv[
        ((size_t)(q0 + w * 16 + r15) * BATCH + b) * E3 +
        h * DH + kc * 32 + quad * 8];

  // ---- stage first K/V tile ----
#pragma unroll
  for (int i = 0; i < 2; ++i) {
    int row = i * 32 + srow;
    int gcb = scb ^ (row & 7);
    load_lds16(kbase + ((size_t)row * BATCH + b) * E3 + gcb * 8,
               Ks[0] + i * 2048 + tid * 8);
    load_lds16(vbase + (size_t)row * S_LEN + gcb * 8,
               Vs[0] + i * 2048 + tid * 8);
  }
  __syncthreads();

  floatx4 of[4];
#pragma unroll
  for (int j = 0; j < 4; ++j) of[j] = (floatx4){0.f, 0.f, 0.f, 0.f};
  float lp = 0.f;

  const float* psb =
      pos_sim + ((size_t)(b * S_LEN + q0 + w * 16 + r15)) * S_LEN + quad * 4;
  __bf16* pw = Ps + w * 1024;

  for (int kt = 0; kt < 32; ++kt) {
    int cur = kt & 1;
    int t0 = kt * 64;
    // ---- pos_sim seeds FIRST (vmcnt wait for seeds leaves staging in flight)
    floatx4 sf[4];
#pragma unroll
    for (int j = 0; j < 4; ++j)
      sf[j] = *(const floatx4*)(psb + t0 + j * 16);
    // ---- stage next K/V tile into the other buffer ----
    if (kt < 31) {
      int tn = t0 + 64;
      int nb = cur ^ 1;
#pragma unroll
      for (int i = 0; i < 2; ++i) {
        int row = i * 32 + srow;
        int gcb = scb ^ (row & 7);
        load_lds16(kbase + ((size_t)(tn + row) * BATCH + b) * E3 + gcb * 8,
                   Ks[nb] + i * 2048 + tid * 8);
        load_lds16(vbase + (size_t)row * S_LEN + tn + gcb * 8,
                   Vs[nb] + i * 2048 + tid * 8);
      }
    }

    // ---- S^T = K Q^T + pos_sim (seeded accumulator) ----
#pragma unroll
    for (int j = 0; j < 4; ++j) {
      int rowk = j * 16 + r15;
      bf16x8 kf0 = *(const bf16x8*)&Ks[cur][rowk * 64 + (quad ^ (rowk & 7)) * 8];
      bf16x8 kf1 = *(const bf16x8*)&Ks[cur][rowk * 64 + ((4 + quad) ^ (rowk & 7)) * 8];
      sf[j] = __builtin_amdgcn_mfma_f32_16x16x32_bf16(kf0, qa[0], sf[j], 0, 0, 0);
      sf[j] = __builtin_amdgcn_mfma_f32_16x16x32_bf16(kf1, qa[1], sf[j], 0, 0, 0);
    }

    // ---- exp (no max), per-lane l, pack P^T -> per-wave LDS ----
#pragma unroll
    for (int j = 0; j < 4; ++j) {
      float e0 = __expf(fminf(sf[j][0], 60.f));
      float e1 = __expf(fminf(sf[j][1], 60.f));
      float e2 = __expf(fminf(sf[j][2], 60.f));
      float e3 = __expf(fminf(sf[j][3], 60.f));
      lp += (e0 + e1) + (e2 + e3);
      __hip_bfloat16 t4[4];
      t4[0] = __float2bfloat16(e0); t4[1] = __float2bfloat16(e1);
      t4[2] = __float2bfloat16(e2); t4[3] = __float2bfloat16(e3);
      int addr = r15 * 64 + (((j * 2 + (quad >> 1)) ^ x7) * 8) + (quad & 1) * 4;
      *(float2*)&pw[addr] = *(float2*)t4;
    }
    __asm__ volatile("s_waitcnt lgkmcnt(0)" ::: "memory");

    // ---- O^T += V^T P^T ----
    bf16x8 pb0 = *(const bf16x8*)&pw[r15 * 64 + ((quad ^ x7) * 8)];
    bf16x8 pb1 = *(const bf16x8*)&pw[r15 * 64 + (((4 + quad) ^ x7) * 8)];
#pragma unroll
    for (int jd = 0; jd < 4; ++jd) {
      int rowd = jd * 16 + r15;
      bf16x8 vb0 = *(const bf16x8*)&Vs[cur][rowd * 64 + (quad ^ (rowd & 7)) * 8];
      bf16x8 vb1 = *(const bf16x8*)&Vs[cur][rowd * 64 + ((4 + quad) ^ (rowd & 7)) * 8];
      of[jd] = __builtin_amdgcn_mfma_f32_16x16x32_bf16(vb0, pb0, of[jd], 0, 0, 0);
      of[jd] = __builtin_amdgcn_mfma_f32_16x16x32_bf16(vb1, pb1, of[jd], 0, 0, 0);
    }
    __syncthreads();   // waves done with bufs[cur]; next-tile staging drained
  }

  // ---- epilogue: reduce l over quads, O^T / l, packed 8B stores ----
  float l = lp;
  l += __shfl_xor(l, 16, 64);
  l += __shfl_xor(l, 32, 64);
  float inv = 1.f / l;
  size_t rbase = ((size_t)(q0 + w * 16 + r15) * BATCH + b) * EMB + h * DH;
#pragma unroll
  for (int jd = 0; jd < 4; ++jd) {
    __hip_bfloat16 o4[4];
    o4[0] = __float2bfloat16(of[jd][0] * inv);
    o4[1] = __float2bfloat16(of[jd][1] * inv);
    o4[2] = __float2bfloat16(of[jd][2] * inv);
    o4[3] = __float2bfloat16(of[jd][3] * inv);
    *(float2*)&ctx[rbase + jd * 16 + quad * 4] = *(float2*)o4;
  }
}

// ---------------- layernorm(x1+x2)*g + b, fp32 out + optional bf16 out -------
__global__ __launch_bounds__(256) void ln_kernel(
    const float* __restrict__ x1, const float* __restrict__ x2,
    const float* __restrict__ g, const float* __restrict__ bb,
    float* __restrict__ out, __hip_bfloat16* __restrict__ out_bf)
{
  int row = blockIdx.x;
  int tid = threadIdx.x;
  const float* p1 = x1 + (size_t)row * EMB;
  const float* p2 = x2 + (size_t)row * EMB;
  float4 v1 = *(const float4*)&p1[tid * 4];
  float4 v2 = *(const float4*)&p2[tid * 4];
  float x[4] = {v1.x + v2.x, v1.y + v2.y, v1.z + v2.z, v1.w + v2.w};
  float s = x[0] + x[1] + x[2] + x[3];
  float s2 = x[0] * x[0] + x[1] * x[1] + x[2] * x[2] + x[3] * x[3];
#pragma unroll
  for (int off = 32; off >= 1; off >>= 1) {
    s  += __shfl_xor(s, off, 64);
    s2 += __shfl_xor(s2, off, 64);
  }
  __shared__ float ws1[4], ws2[4];
  int wid = tid >> 6, lane = tid & 63;
  if (lane == 0) { ws1[wid] = s; ws2[wid] = s2; }
  __syncthreads();
  s  = ws1[0] + ws1[1] + ws1[2] + ws1[3];
  s2 = ws2[0] + ws2[1] + ws2[2] + ws2[3];
  float mean = s * (1.f / EMB);
  float var  = s2 * (1.f / EMB) - mean * mean;
  float inv  = rsqrtf(var + 1e-5f);
  float4 gv = *(const float4*)&g[tid * 4];
  float4 bv = *(const float4*)&bb[tid * 4];
  float4 o;
  o.x = (x[0] - mean) * inv * gv.x + bv.x;
  o.y = (x[1] - mean) * inv * gv.y + bv.y;
  o.z = (x[2] - mean) * inv * gv.z + bv.z;
  o.w = (x[3] - mean) * inv * gv.w + bv.w;
  *(float4*)&out[(size_t)row * EMB + tid * 4] = o;
  if (out_bf) {
    __hip_bfloat16 t[4];
    t[0] = __float2bfloat16(o.x); t[1] = __float2bfloat16(o.y);
    t[2] = __float2bfloat16(o.z); t[3] = __float2bfloat16(o.w);
    *(float2*)&out_bf[(size_t)row * EMB + tid * 4] = *(float2*)t;
  }
}

extern "C" void kernel_launch(void* const* d_in, const int* in_sizes, int n_in,
                              void* d_out, int out_size, void* d_ws, size_t ws_size,
                              hipStream_t stream)
{
  const float* src       = (const float*)d_in[0];
  const float* pos_embed = (const float*)d_in[1];
  const float* in_proj_w = (const float*)d_in[2];
  const float* in_proj_b = (const float*)d_in[3];
  const float* out_w     = (const float*)d_in[4];
  const float* out_b     = (const float*)d_in[5];
  const float* lin1_w    = (const float*)d_in[6];
  const float* lin1_b    = (const float*)d_in[7];
  const float* lin2_w    = (const float*)d_in[8];
  const float* lin2_b    = (const float*)d_in[9];
  const float* ln1_g     = (const float*)d_in[10];
  const float* ln1_b     = (const float*)d_in[11];
  const float* ln2_g     = (const float*)d_in[12];
  const float* ln2_b     = (const float*)d_in[13];
  const float* pos_w     = (const float*)d_in[14];
  const float* pos_b     = (const float*)d_in[15];
  float* out = (float*)d_out;
  float* ws  = (float*)d_ws;

  // ---- workspace layout (float units), peak 31,588,352 floats ≈ 126 MB ----
  __hip_bfloat16* peT    = (__hip_bfloat16*)ws;                // 262,144 el -> 131,072 fl
  float* pos_sim         = ws + 131072;                        // 8,388,608 -> 8,519,680
  __hip_bfloat16* qkv_bf = (__hip_bfloat16*)(ws + 8519680);    // 12,582,912 el -> 14,811,136
  __hip_bfloat16* vT_bf  = (__hip_bfloat16*)(ws + 14811136);   // 4,194,304 el -> 16,908,288
  __hip_bfloat16* src_bf = (__hip_bfloat16*)(ws + 16908288);   // 4,194,304 el -> 19,005,440
  __hip_bfloat16* inw_bf  = (__hip_bfloat16*)(ws + 19005440);  // 3,145,728 el -> 20,578,304
  __hip_bfloat16* outw_bf = (__hip_bfloat16*)(ws + 20578304);  // 1,048,576 el -> 21,102,592
  __hip_bfloat16* ctx_bf = (__hip_bfloat16*)(ws + 21102592);   // 4,194,304 el -> 23,199,744
  __hip_bfloat16* l1w_bf = (__hip_bfloat16*)(ws + 23199744);   // 4,194,304 el -> 25,296,896
  __hip_bfloat16* l2w_bf = (__hip_bfloat16*)(ws + 25296896);   // 4,194,304 el -> 27,394,048
  float* proj            = ws + 27394048;                      // 4,194,304 -> 31,588,352
  // phase-2 reuse (peT/pos_sim/qkv/vT dead after attn):
  __hip_bfloat16* x_bf   = (__hip_bfloat16*)ws;                // 4,194,304 el -> 2,097,152 fl
  float* xbuf            = ws + 2097152;                       // 4,194,304 -> 6,291,456
  __hip_bfloat16* h1_bf  = (__hip_bfloat16*)(ws + 6291456);    // 16,777,216 el -> 14,680,064 fl

  const int M = S_LEN * BATCH;  // 4096 rows, row = s*B + b

  cvt5_kernel<<<8192, 256, 0, stream>>>(
      src, in_proj_w, out_w, lin1_w, lin2_w,
      src_bf, inw_bf, outw_bf, l1w_bf, l2w_bf);
  pe_kernel<<<dim3(S_LEN / 64, BATCH), 64, 0, stream>>>(pos_embed, pos_w, pos_b, peT);
  // pos_sim[b] = peT[b] @ peT[b]^T  (M=N=2048, K=64), fp32 out
  gemm_bf16<4, 4><<<dim3(2048 / 128, 2048 / 128, BATCH), 256, 0, stream>>>(
      peT, peT, nullptr, pos_sim, nullptr, nullptr, 2048, 2048, 64, 0, 0,
      (long)2048 * 64, (long)2048 * 64, (long)2048 * 2048);
  // qkv = src @ in_proj_w^T + b; q pre-scaled 0.125; V cols written to vT_bf
  gemm_bf16<4, 4><<<dim3(E3 / 128, M / 128, 1), 256, 0, stream>>>(
      src_bf, inw_bf, in_proj_b, nullptr, qkv_bf, vT_bf, M, E3, EMB, 0, 1, 0, 0, 0);
  attn_mfma<<<dim3(S_LEN / 64, NH, BATCH), 256, 0, stream>>>(
      qkv_bf, vT_bf, pos_sim, ctx_bf);
  // attn_out = ctx @ out_w^T + b   (N=1024: 64x128 tiles -> 512 blocks)
  gemm_bf16<2, 4><<<dim3(EMB / 128, M / 64, 1), 256, 0, stream>>>(
      ctx_bf, outw_bf, out_b, proj, nullptr, nullptr, M, EMB, EMB, 0, 0, 0, 0, 0);
  ln_kernel<<<dim3(M), 256, 0, stream>>>(src, proj, ln1_g, ln1_b, xbuf, x_bf);
  gemm_bf16<4, 4><<<dim3(FF / 128, M / 128, 1), 256, 0, stream>>>(
      x_bf, l1w_bf, lin1_b, nullptr, h1_bf, nullptr, M, FF, EMB, 1, 0, 0, 0, 0);
  gemm_bf16<2, 4><<<dim3(EMB / 128, M / 64, 1), 256, 0, stream>>>(
      h1_bf, l2w_bf, lin2_b, proj, nullptr, nullptr, M, EMB, FF, 0, 0, 0, 0, 0);
  ln_kernel<<<dim3(M), 256, 0, stream>>>(xbuf, proj, ln2_g, ln2_b, out, nullptr);
}